// Round 6
// baseline (66.161 us; speedup 1.0000x reference)
//
#include <hip/hip_runtime.h>

typedef float f4 __attribute__((ext_vector_type(4)));

#define PAD 68      // LDS row pitch (floats); 68%32=4 spreads banks, 16B-aligned
#define NBLK 256

// ws float layout:
// [0, 3145728)      partials [256][3][4096]  (12.6 MB, clean f4 stores)
// [3145728, +256)   bpart[256]
// [3145984, +2)     cnt (grid barrier), cnt2 (final ticket) — memsetAsync'd

__global__ __launch_bounds__(1024) void fused_all_kernel(
    const float* __restrict__ p1, const float* __restrict__ p2,
    float* __restrict__ partials, float* __restrict__ bpart,
    unsigned* __restrict__ cnt, float* __restrict__ out)
{
    __shared__ float la[32 * PAD];
    __shared__ float lb[32 * PAD];
    __shared__ float nred[64][17];
    __shared__ float sa[32], sb[32];
    __shared__ float red2[16][3][16];   // [wave][gram][entry-offset]
    __shared__ unsigned lastf;
    const int t   = threadIdx.x;
    const int blk = blockIdx.x;
    const int b   = blk >> 5;     // batch 0..7
    const int oi  = blk & 31;     // pooled row strip 0..31

    // ---- phase 1a: pool 4x4 means into LDS [oj][c]  (coalesced 512B rows)
    #pragma unroll
    for (int k = 0; k < 2; ++k) {
        const int idx = k * 1024 + t;     // 0..2047
        const int c   = idx >> 5;
        const int oj  = idx & 31;
        const long off = (long)((b * 64 + c) * 128 + oi * 4) * 128 + oj * 4;
        const float* s1 = p1 + off;
        const float* s2 = p2 + off;
        f4 va = *(const f4*)(s1) + *(const f4*)(s1 + 128)
              + *(const f4*)(s1 + 256) + *(const f4*)(s1 + 384);
        f4 vb = *(const f4*)(s2) + *(const f4*)(s2 + 128)
              + *(const f4*)(s2 + 256) + *(const f4*)(s2 + 384);
        la[oj * PAD + c] = ((va[0] + va[1]) + (va[2] + va[3])) * 0.0625f;
        lb[oj * PAD + c] = ((vb[0] + vb[1]) + (vb[2] + vb[3])) * 0.0625f;
    }
    __syncthreads();

    // ---- phase 1b: row L2 norms over 64 channels
    {
        const int r = t & 31, g = t >> 5;        // g = 0..31
        const int m = g >> 4, q = g & 15;        // input, 4-ch chunk
        const float* src = m ? lb : la;
        float ss = 0.f;
        #pragma unroll
        for (int j = 0; j < 4; ++j) {
            const float v = src[r * PAD + q * 4 + j];
            ss = fmaf(v, v, ss);
        }
        nred[m * 32 + r][q] = ss;
    }
    __syncthreads();
    if (t < 64) {
        const int m = t >> 5, r = t & 31;
        float ss = 0.f;
        #pragma unroll
        for (int q = 0; q < 16; ++q) ss += nred[m * 32 + r][q];
        const float rs = 1.0f / fmaxf(sqrtf(ss), 1e-8f);
        if (m) sb[r] = rs; else sa[r] = rs;
    }
    __syncthreads();

    // ---- scale rows in place
    #pragma unroll
    for (int k = 0; k < 2; ++k) {
        const int idx = k * 1024 + t;
        const int c = idx >> 5, oj = idx & 31;
        la[oj * PAD + c] *= sa[oj];
        lb[oj * PAD + c] *= sb[oj];
    }
    __syncthreads();

    // ---- phase 1c: three 64x64 Grams; 4x4 tiles on threads 0..255 only
    // (b128 LDS reads, 512 KB/block total: LDS-pipe optimal)
    if (t < 256) {
        const int c1 = (t >> 4) * 4;
        const int c2 = (t & 15) * 4;
        f4 aa[4] = {}; f4 ab[4] = {}; f4 bb[4] = {};

        #pragma unroll 8
        for (int r = 0; r < 32; ++r) {
            const f4 a1 = *(const f4*)&la[r * PAD + c1];
            const f4 a2 = *(const f4*)&la[r * PAD + c2];
            const f4 b1 = *(const f4*)&lb[r * PAD + c1];
            const f4 b2 = *(const f4*)&lb[r * PAD + c2];
            #pragma unroll
            for (int i = 0; i < 4; ++i) {
                aa[i] += a2 * a1[i];
                ab[i] += b2 * a1[i];
                bb[i] += b2 * b1[i];
            }
        }

        float* P = partials + (long)blk * 12288;
        #pragma unroll
        for (int i = 0; i < 4; ++i) {
            *(f4*)&P[0 * 4096 + (c1 + i) * 64 + c2] = aa[i];
            *(f4*)&P[1 * 4096 + (c1 + i) * 64 + c2] = ab[i];
            *(f4*)&P[2 * 4096 + (c1 + i) * 64 + c2] = bb[i];
        }
    }

    // ---- grid soft barrier (256 blocks, 1 per CU, co-resident)
    __syncthreads();
    if (t == 0) {
        __hip_atomic_fetch_add(cnt, 1u, __ATOMIC_ACQ_REL,
                               __HIP_MEMORY_SCOPE_AGENT);
        while (__hip_atomic_load(cnt, __ATOMIC_ACQUIRE,
                                 __HIP_MEMORY_SCOPE_AGENT) < NBLK) {}
    }
    __syncthreads();

    // ---- phase 2: block reduces its 16 Gram entries over all 256 partials
    // wave w covers p in [w*16, w*16+16); lane: rep = l>>4 selects gram.
    {
        const int w   = t >> 6;
        const int l   = t & 63;
        const int rep = l >> 4;          // 0..3; gram index, rep==3 idle
        const int eo  = l & 15;
        if (rep < 3) {
            float s = 0.f;
            #pragma unroll
            for (int i = 0; i < 16; ++i)
                s += partials[(long)(w * 16 + i) * 12288 + rep * 4096
                              + blk * 16 + eo];
            red2[w][rep][eo] = s;
        }
    }
    __syncthreads();

    if (t < 16) {
        float s3[3];
        #pragma unroll
        for (int g = 0; g < 3; ++g) {
            float s = 0.f;
            #pragma unroll
            for (int w = 0; w < 16; ++w) s += red2[w][g][t];
            s3[g] = s;
        }
        float v = fmaf(s3[0], s3[0],
                  fmaf(s3[2], s3[2], -2.0f * (s3[1] * s3[1])));
        v += __shfl_xor(v, 1);
        v += __shfl_xor(v, 2);
        v += __shfl_xor(v, 4);
        v += __shfl_xor(v, 8);
        if (t == 0) {
            __hip_atomic_store(&bpart[blk], v, __ATOMIC_RELEASE,
                               __HIP_MEMORY_SCOPE_AGENT);
            unsigned old = __hip_atomic_fetch_add(cnt + 1, 1u,
                                                  __ATOMIC_ACQ_REL,
                                                  __HIP_MEMORY_SCOPE_AGENT);
            lastf = (old == NBLK - 1) ? 1u : 0u;
        }
    }
    __syncthreads();

    if (lastf) {     // only the last-arriving block enters (block-uniform)
        if (t < 64) {
            const f4 vv = *(const f4*)&bpart[t * 4];   // t<64 reads all 256
            float v = (vv[0] + vv[1]) + (vv[2] + vv[3]);
            v += __shfl_xor(v, 1);
            v += __shfl_xor(v, 2);
            v += __shfl_xor(v, 4);
            v += __shfl_xor(v, 8);
            v += __shfl_xor(v, 16);
            v += __shfl_xor(v, 32);
            if (t == 0) out[0] = v * (1.0f / 67108864.0f);  // / 8192^2
        }
    }
}

extern "C" void kernel_launch(void* const* d_in, const int* in_sizes, int n_in,
                              void* d_out, int out_size, void* d_ws, size_t ws_size,
                              hipStream_t stream)
{
    const float* p1 = (const float*)d_in[0];
    const float* p2 = (const float*)d_in[1];
    float* ws       = (float*)d_ws;
    float* partials = ws;                           // 256*12288
    float* bpart    = ws + (long)NBLK * 12288;      // 256
    unsigned* cnt   = (unsigned*)(bpart + NBLK);    // cnt, cnt2

    hipMemsetAsync(cnt, 0, 2 * sizeof(unsigned), stream);
    fused_all_kernel<<<NBLK, 1024, 0, stream>>>(p1, p2, partials, bpart, cnt,
                                                (float*)d_out);
}

// Round 7
// 37.617 us; speedup vs baseline: 1.7588x; 1.7588x over previous
//
#include <hip/hip_runtime.h>

typedef float f4 __attribute__((ext_vector_type(4)));
typedef float f2 __attribute__((ext_vector_type(2)));

#define PAD 68              // LDS row pitch (floats); 68%32=4 spreads banks
#define NPART 256           // gram blocks = partial count
#define PART_STRIDE 12288   // 3 * 64*64 floats per block partial

// ws layout (floats):
// [0, 3145728)      partials [256][3][4096]
// [3145728, +256)   per-block v partials (K2)
// [3146240]         uint counter (K2 ticket; reset by K1 block 0)

__global__ __launch_bounds__(1024) void fused_gram_kernel(
    const float* __restrict__ p1, const float* __restrict__ p2,
    float* __restrict__ partials, unsigned* __restrict__ cnt)
{
    __shared__ float la[32 * PAD];
    __shared__ float lb[32 * PAD];
    __shared__ float nred[64][17];
    __shared__ float sa[32], sb[32];
    const int t  = threadIdx.x;
    const int w  = t >> 6;            // wave 0..15
    const int l  = t & 63;            // lane
    const int b  = blockIdx.x >> 5;   // batch 0..7
    const int oi = blockIdx.x & 31;   // pooled row strip 0..31

    if (blockIdx.x == 0 && t == 0) *cnt = 0u;   // reset K2's ticket each call

    // ---- pool phase: wave w owns channels 4w..4w+3.
    // Per channel: the 4-row strip is 2 KB contiguous; two wave-loads of
    // 1 KB each (lane l -> base + k*256 + l*4 floats). DRAM-friendly:
    // every load instruction is one contiguous 1 KB segment, sequential
    // within the channel chunk.
    {
        const int lj = l & 31;        // pooled col oj this lane produces
        f4 v[2][4][2];
        #pragma unroll
        for (int cc = 0; cc < 4; ++cc) {
            const int c = w * 4 + cc;
            const long base = (long)((b * 64 + c) * 128 + oi * 4) * 128;
            #pragma unroll
            for (int k = 0; k < 2; ++k) {
                v[0][cc][k] = *(const f4*)(p1 + base + k * 256 + l * 4);
                v[1][cc][k] = *(const f4*)(p2 + base + k * 256 + l * 4);
            }
        }
        // lane l, k=0 -> row (l>>5), k=1 -> row 2+(l>>5), cols 4*(l&31)..+3
        #pragma unroll
        for (int m = 0; m < 2; ++m) {
            #pragma unroll
            for (int cc = 0; cc < 4; ++cc) {
                const f4 x = v[m][cc][0];
                const f4 y = v[m][cc][1];
                float s = ((x[0] + x[1]) + (x[2] + x[3]))
                        + ((y[0] + y[1]) + (y[2] + y[3]));
                s += __shfl_xor(s, 32);      // combine rows {0,2} with {1,3}
                if (l < 32) {
                    float* dst = m ? lb : la;
                    dst[lj * PAD + (w * 4 + cc)] = s * 0.0625f;
                }
            }
        }
    }
    __syncthreads();

    // ---- row L2 norms over 64 ch: 32 rows x 2 inputs x 16 chunks of 4 ch
    {
        const int r = t & 31, g = t >> 5;        // g = 0..31
        const int m = g >> 4, q = g & 15;        // input, chunk
        const float* src = m ? lb : la;
        float ss = 0.f;
        #pragma unroll
        for (int j = 0; j < 4; ++j) {
            const float v = src[r * PAD + q * 4 + j];
            ss = fmaf(v, v, ss);
        }
        nred[m * 32 + r][q] = ss;
    }
    __syncthreads();
    if (t < 64) {
        const int m = t >> 5, r = t & 31;
        float ss = 0.f;
        #pragma unroll
        for (int q = 0; q < 16; ++q) ss += nred[m * 32 + r][q];
        const float rs = 1.0f / fmaxf(sqrtf(ss), 1e-8f);
        if (m) sb[r] = rs; else sa[r] = rs;
    }
    __syncthreads();

    // ---- scale rows in place
    #pragma unroll
    for (int k = 0; k < 2; ++k) {
        const int idx = k * 1024 + t;
        const int c = idx >> 5, oj = idx & 31;
        la[oj * PAD + c] *= sa[oj];
        lb[oj * PAD + c] *= sb[oj];
    }
    __syncthreads();

    // ---- three 64x64 channel Grams over this block's 32 rows (as round 3)
    const int c1 = (t >> 5) * 2;      // broadcast within half-wave
    const int c2 = (t & 31) * 2;      // stride-2 across lanes (2-way = free)
    f2 aa0 = {}, aa1 = {}, ab0 = {}, ab1 = {}, bb0 = {}, bb1 = {};

    #pragma unroll 8
    for (int r = 0; r < 32; ++r) {
        const f2 a1 = *(const f2*)&la[r * PAD + c1];
        const f2 a2 = *(const f2*)&la[r * PAD + c2];
        const f2 b1 = *(const f2*)&lb[r * PAD + c1];
        const f2 b2 = *(const f2*)&lb[r * PAD + c2];
        aa0 += a2 * a1[0];  aa1 += a2 * a1[1];
        ab0 += b2 * a1[0];  ab1 += b2 * a1[1];
        bb0 += b2 * b1[0];  bb1 += b2 * b1[1];
    }

    float* P = partials + (long)blockIdx.x * PART_STRIDE;
    *(f2*)&P[0 * 4096 + (c1    ) * 64 + c2] = aa0;
    *(f2*)&P[0 * 4096 + (c1 + 1) * 64 + c2] = aa1;
    *(f2*)&P[1 * 4096 + (c1    ) * 64 + c2] = ab0;
    *(f2*)&P[1 * 4096 + (c1 + 1) * 64 + c2] = ab1;
    *(f2*)&P[2 * 4096 + (c1    ) * 64 + c2] = bb0;
    *(f2*)&P[2 * 4096 + (c1 + 1) * 64 + c2] = bb1;
}

// K2: byte-identical to round 3's (best measured): 256 blocks x 256 threads.
__global__ __launch_bounds__(256) void reduce_kernel(
    const float* __restrict__ partials, float* __restrict__ bpart,
    unsigned* __restrict__ cnt, float* __restrict__ out)
{
    __shared__ float red[3][16][17];
    __shared__ float vred[16];
    __shared__ float fr[256];
    __shared__ unsigned last_flag;
    const int t  = threadIdx.x;
    const int el = t & 15;       // entry within block
    const int pc = t >> 4;       // partial chunk 0..15 (16 partials each)
    const int e  = blockIdx.x * 16 + el;

    float saa = 0.f, sab = 0.f, sbb = 0.f;
    #pragma unroll 4
    for (int i = 0; i < 16; ++i) {
        const float* P = partials + (long)(pc * 16 + i) * PART_STRIDE;
        saa += P[e];
        sab += P[4096 + e];
        sbb += P[8192 + e];
    }
    red[0][el][pc] = saa; red[1][el][pc] = sab; red[2][el][pc] = sbb;
    __syncthreads();

    if (t < 16) {
        float a = 0.f, m = 0.f, bv = 0.f;
        #pragma unroll
        for (int p = 0; p < 16; ++p) {
            a  += red[0][t][p];
            m  += red[1][t][p];
            bv += red[2][t][p];
        }
        vred[t] = fmaf(a, a, fmaf(bv, bv, -2.0f * (m * m)));
    }
    __syncthreads();

    if (t == 0) {
        float s = 0.f;
        #pragma unroll
        for (int i = 0; i < 16; ++i) s += vred[i];
        __hip_atomic_store(&bpart[blockIdx.x], s, __ATOMIC_RELEASE,
                           __HIP_MEMORY_SCOPE_AGENT);
        unsigned old = __hip_atomic_fetch_add(cnt, 1u, __ATOMIC_ACQ_REL,
                                              __HIP_MEMORY_SCOPE_AGENT);
        last_flag = (old == NPART - 1) ? 1u : 0u;
    }
    __syncthreads();

    if (last_flag) {   // block-uniform
        fr[t] = __hip_atomic_load(&bpart[t], __ATOMIC_ACQUIRE,
                                  __HIP_MEMORY_SCOPE_AGENT);
        __syncthreads();
        for (int s2 = 128; s2 > 0; s2 >>= 1) {
            if (t < s2) fr[t] += fr[t + s2];
            __syncthreads();
        }
        if (t == 0) out[0] = fr[0] * (1.0f / 67108864.0f);  // / 8192^2
    }
}

extern "C" void kernel_launch(void* const* d_in, const int* in_sizes, int n_in,
                              void* d_out, int out_size, void* d_ws, size_t ws_size,
                              hipStream_t stream)
{
    const float* p1 = (const float*)d_in[0];
    const float* p2 = (const float*)d_in[1];
    float* ws       = (float*)d_ws;
    float* partials = ws;                                  // 256*12288
    float* bpart    = ws + (long)NPART * PART_STRIDE;      // 256
    unsigned* cnt   = (unsigned*)(ws + 3146240);           // 1

    fused_gram_kernel<<<NPART, 1024, 0, stream>>>(p1, p2, partials, cnt);
    reduce_kernel   <<<NPART, 256, 0, stream>>>(partials, bpart, cnt, (float*)d_out);
}